// Round 5
// baseline (171.269 us; speedup 1.0000x reference)
//
#include <hip/hip_runtime.h>
#include <hip/hip_bf16.h>

#define NROWS 16384   // B*S
#define KD    2048    // D
#define NE    16      // experts
#define ROWS_PER_BLK 64
#define TK    64      // K-floats staged per tile
#define NT    (KD / TK)   // 32 tiles
#define KSPLIT 8

// Fused noisy-router:
//  - x staged to LDS (coalesced, XOR-swizzled, double-buffered 64x64 tiles)
//  - lane = row, wave = K-slice of 8 floats per tile
//  - W loads register-pipelined in 4 expert-groups (double-buffered, VMEM broadcast)
//  - LDS cross-wave reduce, wave0 epilogue (softplus, top-2, 2-way softmax)
// Output buffer FLOAT32: [262144 probs][32768 ids-as-floats].
__global__ __launch_bounds__(512, 2)
void noisy_router_kernel(const float* __restrict__ x,
                         const float* __restrict__ noise,
                         const float* __restrict__ Wfc,
                         const float* __restrict__ bfc,
                         const float* __restrict__ Wns,
                         const float* __restrict__ bns,
                         float* __restrict__ out)
{
    __shared__ float stage[2][ROWS_PER_BLK * TK];      // 32 KB (also epilogue slab)
    __shared__ float redA[NE][ROWS_PER_BLK + 1];       // 4160 B
    __shared__ float redB[NE][ROWS_PER_BLK + 1];       // 4160 B

    const int tid  = threadIdx.x;
    const int lane = tid & 63;
    const int w    = tid >> 6;                         // K-slice id 0..7
    const int wko  = w * 8;                            // K offset within tile

    // ---- staging map: thread loads rows r0 and r0+32, float4 column c4 ----
    const int r0 = tid >> 4;          // 0..31
    const int c4 = tid & 15;          // 0..15
    const int slot = c4 ^ (r0 & 15);
    const int dst0 = r0 * TK + slot * 4;
    const int dst1 = dst0 + 32 * TK;
    const float* xg0 = x + (size_t)(blockIdx.x * ROWS_PER_BLK + r0) * KD + c4 * 4;
    const float* xg1 = xg0 + (size_t)32 * KD;

    // ---- compute-side read offsets: lane l = row l ----
    const int rd0 = lane * TK + ((2 * w)     ^ (lane & 15)) * 4;
    const int rd1 = lane * TK + ((2 * w + 1) ^ (lane & 15)) * 4;

    float accA[NE], accB[NE];
    #pragma unroll
    for (int e = 0; e < NE; ++e) { accA[e] = 0.f; accB[e] = 0.f; }

    float4 a0 = *(const float4*)xg0;    // prologue: tile 0
    float4 a1 = *(const float4*)xg1;

    #pragma unroll 1
    for (int t = 0; t < NT; ++t) {
        float* st = stage[t & 1];
        *(float4*)(st + dst0) = a0;
        *(float4*)(st + dst1) = a1;
        __syncthreads();

        if (t + 1 < NT) {                       // x prefetch for next tile
            a0 = *(const float4*)(xg0 + (size_t)(t + 1) * TK);
            a1 = *(const float4*)(xg1 + (size_t)(t + 1) * TK);
        }

        const float4 xv0 = *(const float4*)(st + rd0);
        const float4 xv1 = *(const float4*)(st + rd1);

        const float* wa = Wfc + t * TK + wko;   // wave-uniform VMEM broadcast
        const float* wb = Wns + t * TK + wko;

        // register double-buffered expert groups (4 experts each, static idx)
        float4 A0[2][4], A1[2][4], B0[2][4], B1[2][4];
        #pragma unroll
        for (int e4 = 0; e4 < 4; ++e4) {
            A0[0][e4] = *(const float4*)(wa + e4 * KD);
            A1[0][e4] = *(const float4*)(wa + e4 * KD + 4);
            B0[0][e4] = *(const float4*)(wb + e4 * KD);
            B1[0][e4] = *(const float4*)(wb + e4 * KD + 4);
        }
        #pragma unroll
        for (int g = 0; g < 4; ++g) {
            const int cur = g & 1, nxt = cur ^ 1;
            if (g < 3) {
                #pragma unroll
                for (int e4 = 0; e4 < 4; ++e4) {
                    const int e = (g + 1) * 4 + e4;
                    A0[nxt][e4] = *(const float4*)(wa + e * KD);
                    A1[nxt][e4] = *(const float4*)(wa + e * KD + 4);
                    B0[nxt][e4] = *(const float4*)(wb + e * KD);
                    B1[nxt][e4] = *(const float4*)(wb + e * KD + 4);
                }
            }
            #pragma unroll
            for (int e4 = 0; e4 < 4; ++e4) {
                const int e = g * 4 + e4;
                const float4 a0v = A0[cur][e4], a1v = A1[cur][e4];
                const float4 b0v = B0[cur][e4], b1v = B1[cur][e4];
                accA[e] = fmaf(xv0.x, a0v.x, accA[e]);
                accA[e] = fmaf(xv0.y, a0v.y, accA[e]);
                accA[e] = fmaf(xv0.z, a0v.z, accA[e]);
                accA[e] = fmaf(xv0.w, a0v.w, accA[e]);
                accA[e] = fmaf(xv1.x, a1v.x, accA[e]);
                accA[e] = fmaf(xv1.y, a1v.y, accA[e]);
                accA[e] = fmaf(xv1.z, a1v.z, accA[e]);
                accA[e] = fmaf(xv1.w, a1v.w, accA[e]);
                accB[e] = fmaf(xv0.x, b0v.x, accB[e]);
                accB[e] = fmaf(xv0.y, b0v.y, accB[e]);
                accB[e] = fmaf(xv0.z, b0v.z, accB[e]);
                accB[e] = fmaf(xv0.w, b0v.w, accB[e]);
                accB[e] = fmaf(xv1.x, b1v.x, accB[e]);
                accB[e] = fmaf(xv1.y, b1v.y, accB[e]);
                accB[e] = fmaf(xv1.z, b1v.z, accB[e]);
                accB[e] = fmaf(xv1.w, b1v.w, accB[e]);
            }
        }
    }
    __syncthreads();   // loop has no trailing barrier; protect slab reuse

    // ---- epilogue: reuse stage[] as slab[KSPLIT][64][16] (8192 floats) ----
    float* slab = &stage[0][0];

    #pragma unroll
    for (int j = 0; j < NE; ++j) slab[w * 1024 + lane * 16 + j] = accA[j];
    __syncthreads();
    {
        const int idx = tid * 2;           // 1024 (row,out) pairs
        const int r   = idx >> 4;
        const int o   = idx & 15;
        float s0 = 0.f, s1 = 0.f;
        #pragma unroll
        for (int v = 0; v < KSPLIT; ++v) {
            s0 += slab[v * 1024 + r * 16 + o];
            s1 += slab[v * 1024 + r * 16 + o + 1];
        }
        redA[o][r]     = s0 + bfc[o];
        redA[o + 1][r] = s1 + bfc[o + 1];
    }
    __syncthreads();

    #pragma unroll
    for (int j = 0; j < NE; ++j) slab[w * 1024 + lane * 16 + j] = accB[j];
    __syncthreads();
    {
        const int idx = tid * 2;
        const int r   = idx >> 4;
        const int o   = idx & 15;
        float s0 = 0.f, s1 = 0.f;
        #pragma unroll
        for (int v = 0; v < KSPLIT; ++v) {
            s0 += slab[v * 1024 + r * 16 + o];
            s1 += slab[v * 1024 + r * 16 + o + 1];
        }
        redB[o][r]     = s0 + bns[o];
        redB[o + 1][r] = s1 + bns[o + 1];
    }
    __syncthreads();

    // ---- final per-row: softplus noise, top-2, sparse softmax ----
    if (tid < ROWS_PER_BLK) {
        const int r = tid;
        const size_t grow = (size_t)blockIdx.x * ROWS_PER_BLK + r;
        const float* nzp = noise + grow * NE;

        float m1 = -1e30f, m2 = -1e30f;
        int i1 = 0, i2 = 0;
        #pragma unroll
        for (int j = 0; j < NE; ++j) {
            const float z  = redB[j][r];
            const float sp = fmaxf(z, 0.f) + log1pf(expf(-fabsf(z)));  // jax softplus
            const float v  = fmaf(nzp[j], sp, redA[j][r]);
            if (v > m1)      { m2 = m1; i2 = i1; m1 = v; i1 = j; }     // ties -> lower idx
            else if (v > m2) { m2 = v;  i2 = j; }
        }
        const float e2  = expf(m2 - m1);
        const float inv = 1.f / (1.f + e2);

        float* po = out + grow * NE;
        #pragma unroll
        for (int j = 0; j < NE; ++j) {
            po[j] = (j == i1) ? inv : ((j == i2) ? e2 * inv : 0.f);
        }
        float* pi = out + (size_t)NROWS * NE + grow * 2;
        pi[0] = (float)i1;
        pi[1] = (float)i2;
    }
}

extern "C" void kernel_launch(void* const* d_in, const int* in_sizes, int n_in,
                              void* d_out, int out_size, void* d_ws, size_t ws_size,
                              hipStream_t stream)
{
    const float* x     = (const float*)d_in[0];
    const float* noise = (const float*)d_in[1];
    const float* Wfc   = (const float*)d_in[2];
    const float* bfc   = (const float*)d_in[3];
    const float* Wns   = (const float*)d_in[4];
    const float* bns   = (const float*)d_in[5];
    float* out = (float*)d_out;

    noisy_router_kernel<<<NROWS / ROWS_PER_BLK, 512, 0, stream>>>(
        x, noise, Wfc, bfc, Wns, bns, out);
}

// Round 6
// 145.762 us; speedup vs baseline: 1.1750x; 1.1750x over previous
//
#include <hip/hip_runtime.h>
#include <hip/hip_bf16.h>

#define NROWS 16384   // B*S
#define KD    2048    // D
#define NE    16      // experts
#define ROWS_PER_WAVE 8
#define WAVES_PER_BLK 4
#define ROWS_PER_BLK  (ROWS_PER_WAVE * WAVES_PER_BLK)   // 32
#define NCHUNK (KD / 32)   // 64 k-chunks of 32 floats

// Barrier-free fused noisy-router:
//  - wave owns 8 rows; lane = (row lane>>3, k-seg lane&7); no LDS, no syncthreads
//  - x: lane loads float4 per 32-float chunk (8x128B contiguous per wave = 16
//    fully-used lines/instr); W: per-lane VMEM float4 loads (L1/L2-resident)
//  - shfl_xor butterfly over k-segs; leader lanes do softplus/top-2/softmax
// Output FLOAT32: [262144 probs][32768 ids-as-floats].
__global__ __launch_bounds__(256, 2)
void noisy_router_kernel(const float* __restrict__ x,
                         const float* __restrict__ noise,
                         const float* __restrict__ Wfc,
                         const float* __restrict__ bfc,
                         const float* __restrict__ Wns,
                         const float* __restrict__ bns,
                         float* __restrict__ out)
{
    const int tid  = threadIdx.x;
    const int lane = tid & 63;
    const int wid  = tid >> 6;            // 0..3
    const int seg  = lane & 7;            // k-segment within 32-float chunk
    const int rsub = lane >> 3;           // 0..7
    const int row  = blockIdx.x * ROWS_PER_BLK + wid * ROWS_PER_WAVE + rsub;

    const float* xl = x   + (size_t)row * KD + seg * 4;
    const float* wa = Wfc + seg * 4;
    const float* wb = Wns + seg * 4;

    float accA[NE], accB[NE];
    #pragma unroll
    for (int e = 0; e < NE; ++e) { accA[e] = 0.f; accB[e] = 0.f; }

    float4 xv = *(const float4*)xl;       // prologue chunk 0

    #pragma unroll 2
    for (int t = 0; t < NCHUNK; ++t) {
        float4 xn;
        if (t + 1 < NCHUNK) xn = *(const float4*)(xl + (t + 1) * 32);

        const float* wat = wa + t * 32;
        const float* wbt = wb + t * 32;
        #pragma unroll
        for (int e = 0; e < NE; ++e) {
            const float4 a = *(const float4*)(wat + e * KD);
            const float4 b = *(const float4*)(wbt + e * KD);
            accA[e] = fmaf(xv.x, a.x, accA[e]);
            accA[e] = fmaf(xv.y, a.y, accA[e]);
            accA[e] = fmaf(xv.z, a.z, accA[e]);
            accA[e] = fmaf(xv.w, a.w, accA[e]);
            accB[e] = fmaf(xv.x, b.x, accB[e]);
            accB[e] = fmaf(xv.y, b.y, accB[e]);
            accB[e] = fmaf(xv.z, b.z, accB[e]);
            accB[e] = fmaf(xv.w, b.w, accB[e]);
        }
        if (t + 1 < NCHUNK) xv = xn;
    }

    // ---- butterfly reduce over the 8 k-segments (masks 1,2,4 stay in-group) ----
    #pragma unroll
    for (int e = 0; e < NE; ++e) {
        accA[e] += __shfl_xor(accA[e], 1);
        accA[e] += __shfl_xor(accA[e], 2);
        accA[e] += __shfl_xor(accA[e], 4);
        accB[e] += __shfl_xor(accB[e], 1);
        accB[e] += __shfl_xor(accB[e], 2);
        accB[e] += __shfl_xor(accB[e], 4);
    }

    // ---- leader lane per row: softplus noise, top-2, sparse softmax ----
    if (seg == 0) {
        const size_t grow = (size_t)row;
        const float* nzp = noise + grow * NE;

        float m1 = -1e30f, m2 = -1e30f;
        int i1 = 0, i2 = 0;
        #pragma unroll
        for (int j = 0; j < NE; ++j) {
            const float z  = accB[j] + bns[j];
            const float sp = fmaxf(z, 0.f) + log1pf(expf(-fabsf(z)));  // jax softplus
            const float v  = fmaf(nzp[j], sp, accA[j] + bfc[j]);
            if (v > m1)      { m2 = m1; i2 = i1; m1 = v; i1 = j; }     // ties -> lower idx
            else if (v > m2) { m2 = v;  i2 = j; }
        }
        const float e2  = expf(m2 - m1);
        const float inv = 1.f / (1.f + e2);

        float* po = out + grow * NE;
        #pragma unroll
        for (int j = 0; j < NE; ++j) {
            po[j] = (j == i1) ? inv : ((j == i2) ? e2 * inv : 0.f);
        }
        float* pi = out + (size_t)NROWS * NE + grow * 2;
        pi[0] = (float)i1;
        pi[1] = (float)i2;
    }
}

extern "C" void kernel_launch(void* const* d_in, const int* in_sizes, int n_in,
                              void* d_out, int out_size, void* d_ws, size_t ws_size,
                              hipStream_t stream)
{
    const float* x     = (const float*)d_in[0];
    const float* noise = (const float*)d_in[1];
    const float* Wfc   = (const float*)d_in[2];
    const float* bfc   = (const float*)d_in[3];
    const float* Wns   = (const float*)d_in[4];
    const float* bns   = (const float*)d_in[5];
    float* out = (float*)d_out;

    noisy_router_kernel<<<NROWS / ROWS_PER_BLK, 256, 0, stream>>>(
        x, noise, Wfc, bfc, Wns, bns, out);
}

// Round 7
// 91.315 us; speedup vs baseline: 1.8756x; 1.5962x over previous
//
#include <hip/hip_runtime.h>
#include <hip/hip_bf16.h>

#define NROWS 16384   // B*S
#define KD    2048    // D
#define NE    16      // experts
#define ROWS_PER_WAVE 8
#define WAVES_PER_BLK 4
#define ROWS_PER_BLK  (ROWS_PER_WAVE * WAVES_PER_BLK)   // 32
#define TK    256                  // K-floats per staged W tile
#define NTILE (KD / TK)            // 8
#define CPT   (TK / 32)            // 8 chunks per tile
#define NCHUNK (KD / 32)           // 64 global chunks

// Fused noisy-router, v7:
//  - wave owns 8 rows; lane = (row lane>>3, k-seg lane&7); butterfly epilogue
//  - W staged to LDS via async global_load_lds (double-buffered 2x32KB tiles,
//    one tile prefetched under previous tile's compute; __syncthreads drains)
//  - compute reads W via ds_read_b128 broadcast (8 distinct addrs, 128B span,
//    conflict-free); x per-lane VMEM float4 with 1-chunk prefetch
// Output FLOAT32: [262144 probs][32768 ids-as-floats].

__device__ __forceinline__ void gload_lds16(const float* g, float* l) {
    __builtin_amdgcn_global_load_lds(
        (const __attribute__((address_space(1))) void*)g,
        (__attribute__((address_space(3))) void*)l,
        16, 0, 0);
}

__global__ __launch_bounds__(256, 2)
void noisy_router_kernel(const float* __restrict__ x,
                         const float* __restrict__ noise,
                         const float* __restrict__ Wfc,
                         const float* __restrict__ bfc,
                         const float* __restrict__ Wns,
                         const float* __restrict__ bns,
                         float* __restrict__ out)
{
    // W-stack tile: rows 0..15 = Wfc experts, 16..31 = Wns experts; [32][TK]
    __shared__ float wtile[2][32 * TK];   // 65536 B

    const int tid  = threadIdx.x;
    const int lane = tid & 63;
    const int w    = tid >> 6;            // 0..3
    const int seg  = lane & 7;            // k-segment within 32-float chunk
    const int rsub = lane >> 3;           // 0..7
    const int row  = blockIdx.x * ROWS_PER_BLK + w * ROWS_PER_WAVE + rsub;

    const float* xl = x + (size_t)row * KD + seg * 4;

    float accA[NE], accB[NE];
    #pragma unroll
    for (int e = 0; e < NE; ++e) { accA[e] = 0.f; accB[e] = 0.f; }

    // ---- stage tile 0 (wave w stages W-stack rows w*8 .. w*8+7) ----
    // row r<16 -> Wfc[r], r>=16 -> Wns[r-16]; per instr: wave writes one
    // 1KB expert-row segment, LDS dest = uniform base + lane*16 (legal form).
    {
        #pragma unroll
        for (int i = 0; i < 8; ++i) {
            const int r = w * 8 + i;
            const float* g = (r < 16 ? Wfc + (size_t)r * KD
                                     : Wns + (size_t)(r - 16) * KD) + lane * 4;
            gload_lds16(g, &wtile[0][r * TK + lane * 4]);
        }
    }

    float4 xv = *(const float4*)xl;       // prologue x chunk 0

    #pragma unroll 1
    for (int t = 0; t < NTILE; ++t) {
        __syncthreads();                  // drains vmcnt -> tile t staged; buf reuse safe

        if (t + 1 < NTILE) {              // async-stage next tile under this compute
            const int k0 = (t + 1) * TK;
            float* dst = &wtile[(t + 1) & 1][0];
            #pragma unroll
            for (int i = 0; i < 8; ++i) {
                const int r = w * 8 + i;
                const float* g = (r < 16 ? Wfc + (size_t)r * KD
                                         : Wns + (size_t)(r - 16) * KD) + k0 + lane * 4;
                gload_lds16(g, dst + r * TK + lane * 4);
            }
        }

        const float* wt = &wtile[t & 1][0];
        #pragma unroll 2
        for (int c = 0; c < CPT; ++c) {
            const int tg = t * CPT + c;   // global chunk index
            float4 xn;
            if (tg + 1 < NCHUNK) xn = *(const float4*)(xl + (tg + 1) * 32);

            const float* wk = wt + c * 32 + seg * 4;
            #pragma unroll
            for (int e = 0; e < NE; ++e) {
                const float4 a = *(const float4*)(wk + e * TK);
                const float4 b = *(const float4*)(wk + (16 + e) * TK);
                accA[e] = fmaf(xv.x, a.x, accA[e]);
                accA[e] = fmaf(xv.y, a.y, accA[e]);
                accA[e] = fmaf(xv.z, a.z, accA[e]);
                accA[e] = fmaf(xv.w, a.w, accA[e]);
                accB[e] = fmaf(xv.x, b.x, accB[e]);
                accB[e] = fmaf(xv.y, b.y, accB[e]);
                accB[e] = fmaf(xv.z, b.z, accB[e]);
                accB[e] = fmaf(xv.w, b.w, accB[e]);
            }
            if (tg + 1 < NCHUNK) xv = xn;
        }
    }

    // ---- butterfly reduce over the 8 k-segments (masks 1,2,4 stay in-group) ----
    #pragma unroll
    for (int e = 0; e < NE; ++e) {
        accA[e] += __shfl_xor(accA[e], 1);
        accA[e] += __shfl_xor(accA[e], 2);
        accA[e] += __shfl_xor(accA[e], 4);
        accB[e] += __shfl_xor(accB[e], 1);
        accB[e] += __shfl_xor(accB[e], 2);
        accB[e] += __shfl_xor(accB[e], 4);
    }

    // ---- leader lane per row: softplus noise, top-2, sparse softmax ----
    if (seg == 0) {
        const size_t grow = (size_t)row;
        const float* nzp = noise + grow * NE;

        float m1 = -1e30f, m2 = -1e30f;
        int i1 = 0, i2 = 0;
        #pragma unroll
        for (int j = 0; j < NE; ++j) {
            const float z  = accB[j] + bns[j];
            const float sp = fmaxf(z, 0.f) + log1pf(expf(-fabsf(z)));  // jax softplus
            const float v  = fmaf(nzp[j], sp, accA[j] + bfc[j]);
            if (v > m1)      { m2 = m1; i2 = i1; m1 = v; i1 = j; }     // ties -> lower idx
            else if (v > m2) { m2 = v;  i2 = j; }
        }
        const float e2  = expf(m2 - m1);
        const float inv = 1.f / (1.f + e2);

        float* po = out + grow * NE;
        #pragma unroll
        for (int j = 0; j < NE; ++j) {
            po[j] = (j == i1) ? inv : ((j == i2) ? e2 * inv : 0.f);
        }
        float* pi = out + (size_t)NROWS * NE + grow * 2;
        pi[0] = (float)i1;
        pi[1] = (float)i2;
    }
}

extern "C" void kernel_launch(void* const* d_in, const int* in_sizes, int n_in,
                              void* d_out, int out_size, void* d_ws, size_t ws_size,
                              hipStream_t stream)
{
    const float* x     = (const float*)d_in[0];
    const float* noise = (const float*)d_in[1];
    const float* Wfc   = (const float*)d_in[2];
    const float* bfc   = (const float*)d_in[3];
    const float* Wns   = (const float*)d_in[4];
    const float* bns   = (const float*)d_in[5];
    float* out = (float*)d_out;

    noisy_router_kernel<<<NROWS / ROWS_PER_BLK, 256, 0, stream>>>(
        x, noise, Wfc, bfc, Wns, bns, out);
}